// Round 15
// baseline (1296.770 us; speedup 1.0000x reference)
//
#include <hip/hip_runtime.h>
#include <cstdint>
#include <cstddef>

#define BB 8
#define NN 4096
#define FF 64
#define SS 2048
#define KK 64
#define H1c 64
#define H2c 64
#define H3c 128
#define R2 0.04f
#define CAPQ 304   // ball candidate cap (mean 137, +14 sigma safe)
#define QRANK 5    // ceil(CAPQ/64)
#define NY1 240    // consumer blocks; grid = 8+1+240 = 249 <= 256 CUs

typedef unsigned long long ull;
typedef __attribute__((ext_vector_type(4))) float f32x4;
typedef __attribute__((ext_vector_type(8))) short bf16x8;

__device__ __forceinline__ float d2_exact(float ax, float ay, float az,
                                          float bx, float by, float bz) {
  float dx = __fsub_rn(ax, bx);
  float dy = __fsub_rn(ay, by);
  float dz = __fsub_rn(az, bz);
  return __fadd_rn(__fadd_rn(__fmul_rn(dx, dx), __fmul_rn(dy, dy)), __fmul_rn(dz, dz));
}

__device__ __forceinline__ unsigned short f2bf(float f) {
  unsigned u = __float_as_uint(f);
  return (unsigned short)((u + 0x7fffu + ((u >> 16) & 1u)) >> 16);
}

#define WAVE_MAX_DPP(v)                                                        \
  do {                                                                         \
    v = max(v, __builtin_amdgcn_update_dpp(0, v, 0x111, 0xf, 0xf, true));      \
    v = max(v, __builtin_amdgcn_update_dpp(0, v, 0x112, 0xf, 0xf, true));      \
    v = max(v, __builtin_amdgcn_update_dpp(0, v, 0x114, 0xf, 0xf, true));      \
    v = max(v, __builtin_amdgcn_update_dpp(0, v, 0x118, 0xf, 0xf, true));      \
    v = max(v, __builtin_amdgcn_update_dpp(0, v, 0x142, 0xf, 0xf, true));      \
    v = max(v, __builtin_amdgcn_update_dpp(0, v, 0x143, 0xf, 0xf, true));      \
  } while (0)

// One kernel, 249 blocks (all co-resident):
//  blocks 0-7   : FPS (R12 per-step body verbatim) + per-256-step burst
//                 publication (pos_out readback -> posw atomics -> flag)
//  block  8     : weight/plane prep
//  blocks 9-248 : y1 GEMM, then gated ball-query + MFMA MLP items
__global__ __launch_bounds__(512) void fused_kernel(
    const float* __restrict__ pos, const float* __restrict__ x,
    const float* __restrict__ W1, const float* __restrict__ b1,
    const float* __restrict__ W2, const float* __restrict__ W3,
    const float* __restrict__ b2, const float* __restrict__ b3,
    float* __restrict__ pos_out, float* __restrict__ batch_out,
    unsigned short* __restrict__ y1b, unsigned short* __restrict__ w2p,
    unsigned short* __restrict__ w3p, float* __restrict__ xpln,
    float* __restrict__ ypln, float* __restrict__ zpln,
    float* __restrict__ posw, int* __restrict__ flags, int* __restrict__ ycnt,
    float* __restrict__ x_out) {
  __shared__ __align__(16) char smem[49408];  // fps plds | consumer kc/h2t/red/nbl/cc
  __shared__ ull skey[2][8];
  __shared__ float xs[64][65];                      // y1 staging
  __shared__ __align__(16) unsigned short lw2[4096];
  __shared__ __align__(16) unsigned short lw3[8192];
  __shared__ float w1r[3][64];
  const int tid = threadIdx.x;
  const int lane = tid & 63, wv = tid >> 6;

  if (blockIdx.x < BB) {
    // ================= FPS role (R12 body + burst publication) ========
    float* plds = (float*)smem;
    const int b = blockIdx.x;
    const float4* src = (const float4*)(pos + (size_t)b * NN * 3);
    float4* dstl = (float4*)plds;
#pragma unroll
    for (int k = 0; k < 6; ++k) dstl[tid + k * 512] = src[tid + k * 512];
    __syncthreads();

    float px[8], py[8], pz[8], dmin[8];
#pragma unroll
    for (int i = 0; i < 8; ++i) {
      int p = tid * 8 + i;
      px[i] = plds[p * 3 + 0];
      py[i] = plds[p * 3 + 1];
      pz[i] = plds[p * 3 + 2];
      dmin[i] = INFINITY;
    }
    float cx = plds[0], cy = plds[1], cz = plds[2];

    for (int s = 0; s < SS; ++s) {
      if (tid == 0) {
        int o = b * SS + s;
        pos_out[o * 3 + 0] = cx;
        pos_out[o * 3 + 1] = cy;
        pos_out[o * 3 + 2] = cz;
      }
#pragma unroll
      for (int i = 0; i < 8; ++i) {
        float d = d2_exact(px[i], py[i], pz[i], cx, cy, cz);
        dmin[i] = fminf(dmin[i], d);
      }
      float m0 = fmaxf(fmaxf(dmin[0], dmin[1]), fmaxf(dmin[2], dmin[3]));
      float m1 = fmaxf(fmaxf(dmin[4], dmin[5]), fmaxf(dmin[6], dmin[7]));
      const float lmax = fmaxf(m0, m1);
      int lidx = 0;
#pragma unroll
      for (int i = 7; i >= 0; --i)
        if (__float_as_int(dmin[i]) == __float_as_int(lmax)) lidx = i;

      const int lv = __float_as_int(lmax);
      int v = lv;
      WAVE_MAX_DPP(v);
      const int wmax = __builtin_amdgcn_readlane(v, 63);
      const ull bal = __ballot(lv == wmax);
      const int wl = (int)__builtin_ctzll(bal);
      const int wli = __builtin_amdgcn_readlane(lidx, wl);
      const int widx = ((wv << 6) + wl) * 8 + wli;
      const int buf = s & 1;
      if (lane == 0)
        skey[buf][wv] = ((ull)(unsigned)wmax << 32) | (unsigned)(~widx);
      __syncthreads();

      ull ka = skey[buf][0];
#pragma unroll
      for (int q = 1; q < 8; ++q) {
        ull kq = skey[buf][q];
        if (kq > ka) ka = kq;
      }
      const int cur = (int)(~(unsigned)(ka & 0xffffffffu));
      cx = plds[cur * 3 + 0];
      cy = plds[cur * 3 + 1];
      cz = plds[cur * 3 + 2];

      // ---- burst publication: off the per-step critical path ----
      if ((s & 255) == 255) {
        const int k = s >> 8;
        const int base = b * SS * 3 + k * 768;
        // chunk-k centroids are L2-visible (tid0's stores drained at the
        // mid-step barrier); re-read and write-through to coherence point
        for (int i = tid; i < 768; i += 512) {
          float vv = pos_out[base + i];
          __hip_atomic_store(&posw[base + i], vv, __ATOMIC_RELAXED,
                             __HIP_MEMORY_SCOPE_AGENT);
        }
        __syncthreads();  // drains every wave's vmcnt -> posw chunk complete
        if (tid == 0)
          __hip_atomic_store(&flags[(b * 8 + k) * 32], 1, __ATOMIC_RELAXED,
                             __HIP_MEMORY_SCOPE_AGENT);
      }
    }
    for (int i = tid; i < SS; i += 512) batch_out[b * SS + i] = (float)b;
    return;
  }

  if (blockIdx.x == BB) {
    // ================= prep role =================
    for (int e = tid; e < 4096; e += 512) {
      int j = e & 7, l = (e >> 3) & 63, s = (e >> 9) & 1, c = e >> 10;
      w2p[e] = f2bf(W2[(s * 32 + 8 * (l >> 4) + j) * H2c + c * 16 + (l & 15)]);
    }
    for (int e = tid; e < 8192; e += 512) {
      int j = e & 7, l = (e >> 3) & 63, s = (e >> 9) & 1, c = e >> 10;
      w3p[e] = f2bf(W3[(s * 32 + 8 * (l >> 4) + j) * H3c + c * 16 + (l & 15)]);
    }
    for (int i = tid; i < BB * NN; i += 512) {
      xpln[i] = pos[3 * i + 0];
      ypln[i] = pos[3 * i + 1];
      zpln[i] = pos[3 * i + 2];
    }
    __syncthreads();
    if (tid == 0)
      __hip_atomic_fetch_add(ycnt, 1, __ATOMIC_RELEASE, __HIP_MEMORY_SCOPE_AGENT);
    return;
  }

  // ================= consumer role =================
  const int cid = blockIdx.x - BB - 1;  // 0..NY1-1

  // ---- phase A: y1 = x @ W1[0:64,:] + b1 -> bf16 ----
  for (int t = cid; t < 512; t += NY1) {
    const int r0 = t * 64;
    const float4* src = (const float4*)(x + (size_t)r0 * FF);
#pragma unroll
    for (int q = 0; q < 2; q++) {
      int p = tid + q * 512;
      float4 v = src[p];
      int row = (p * 4) >> 6, col = (p * 4) & 63;
      xs[row][col + 0] = v.x;
      xs[row][col + 1] = v.y;
      xs[row][col + 2] = v.z;
      xs[row][col + 3] = v.w;
    }
    __syncthreads();
    const int c4 = (tid & 15) * 4, kb = (tid >> 4) * 2;
    float acc[2][4];
#pragma unroll
    for (int kq = 0; kq < 2; kq++) {
      acc[kq][0] = b1[c4 + 0];
      acc[kq][1] = b1[c4 + 1];
      acc[kq][2] = b1[c4 + 2];
      acc[kq][3] = b1[c4 + 3];
    }
    for (int f = 0; f < FF; ++f) {
      float4 w = *(const float4*)(W1 + f * H1c + c4);
#pragma unroll
      for (int kq = 0; kq < 2; kq++) {
        float a = xs[kb + kq][f];
        acc[kq][0] += a * w.x;
        acc[kq][1] += a * w.y;
        acc[kq][2] += a * w.z;
        acc[kq][3] += a * w.w;
      }
    }
#pragma unroll
    for (int kq = 0; kq < 2; kq++) {
      ushort4 o;
      o.x = f2bf(acc[kq][0]);
      o.y = f2bf(acc[kq][1]);
      o.z = f2bf(acc[kq][2]);
      o.w = f2bf(acc[kq][3]);
      *(ushort4*)(y1b + (size_t)(r0 + kb + kq) * H1c + c4) = o;
    }
    __syncthreads();
  }
  if (tid == 0)
    __hip_atomic_fetch_add(ycnt, 1, __ATOMIC_RELEASE, __HIP_MEMORY_SCOPE_AGENT);

  // ---- gate: all y1 + prep done (tid0 polls; one cache-inv acquire) ----
  if (tid == 0) {
    while (__hip_atomic_load(ycnt, __ATOMIC_RELAXED, __HIP_MEMORY_SCOPE_AGENT) <
           NY1 + 1)
      __builtin_amdgcn_s_sleep(64);
    (void)__hip_atomic_load(ycnt, __ATOMIC_ACQUIRE, __HIP_MEMORY_SCOPE_AGENT);
  }
  __syncthreads();

  // ---- stage weights ----
  {
    const uint4* s2 = (const uint4*)w2p;
    uint4* d2v = (uint4*)lw2;
    for (int i = tid; i < 512; i += 512) d2v[i] = s2[i];
    const uint4* s3 = (const uint4*)w3p;
    uint4* d3v = (uint4*)lw3;
    for (int i = tid; i < 1024; i += 512) d3v[i] = s3[i];
    if (tid < 192) w1r[tid / 64][tid % 64] = W1[(64 + tid / 64) * H1c + (tid % 64)];
  }
  __syncthreads();
  const bf16x8* w2f = (const bf16x8*)lw2;
  const bf16x8* w3f = (const bf16x8*)lw3;

  // consumer LDS views inside smem
  ull(*kc)[CAPQ] = (ull(*)[CAPQ])(smem);                        // 19456 B
  unsigned short(*h2t)[16][88] = (unsigned short(*)[16][88])(smem + 19456);
  float(*red)[128] = (float(*)[128])(smem + 41984);             // 4096 B
  int(*nbl)[64] = (int(*)[64])(smem + 46080);                   // 2048 B
  float(*cc)[4] = (float(*)[4])(smem + 48128);                  // 128 B

  const int lrow = lane & 15, g16 = lane >> 4;

  // ---- item loop: 2048 items x 8 centroids, chunk-major order ----
  for (int it = cid; it < 2048; it += NY1) {
    const int k = it >> 8;            // chunk 0..7
    const int rr = it & 255;
    const int b = rr >> 5;            // cloud
    const int j32 = rr & 31;
    const int g0 = b * SS + k * 256 + j32 * 8;

    if (tid == 0) {
      while (__hip_atomic_load(&flags[(b * 8 + k) * 32], __ATOMIC_RELAXED,
                               __HIP_MEMORY_SCOPE_AGENT) == 0)
        __builtin_amdgcn_s_sleep(64);
    }
    __syncthreads();

    // phase 1: wave wv ball-queries centroid g0+wv
    {
      const int g = g0 + wv;
      const float cx = __hip_atomic_load(&posw[g * 3 + 0], __ATOMIC_RELAXED,
                                         __HIP_MEMORY_SCOPE_AGENT);
      const float cy = __hip_atomic_load(&posw[g * 3 + 1], __ATOMIC_RELAXED,
                                         __HIP_MEMORY_SCOPE_AGENT);
      const float cz = __hip_atomic_load(&posw[g * 3 + 2], __ATOMIC_RELAXED,
                                         __HIP_MEMORY_SCOPE_AGENT);
      if (lane == 0) {
        cc[wv][0] = cx;
        cc[wv][1] = cy;
        cc[wv][2] = cz;
      }
      const float4* xp4 = (const float4*)(xpln + (size_t)b * NN);
      const float4* yp4 = (const float4*)(ypln + (size_t)b * NN);
      const float4* zp4 = (const float4*)(zpln + (size_t)b * NN);
      const ull lt = (1ull << lane) - 1ull;
      int cnt = 0;
      for (int t = 0; t < 16; ++t) {
        const int f4 = t * 64 + lane;
        float4 xv = xp4[f4], yv = yp4[f4], zv = zp4[f4];
        const int j0 = f4 * 4;
        float dd[4];
        dd[0] = d2_exact(xv.x, yv.x, zv.x, cx, cy, cz);
        dd[1] = d2_exact(xv.y, yv.y, zv.y, cx, cy, cz);
        dd[2] = d2_exact(xv.z, yv.z, zv.z, cx, cy, cz);
        dd[3] = d2_exact(xv.w, yv.w, zv.w, cx, cy, cz);
#pragma unroll
        for (int e = 0; e < 4; ++e) {
          bool pred = (dd[e] <= R2);
          ull mask = __ballot(pred);
          if (pred) {
            int p = cnt + (int)__popcll(mask & lt);
            if (p < CAPQ)
              kc[wv][p] = ((ull)__float_as_uint(dd[e]) << 32) | (unsigned)(j0 + e);
          }
          cnt += (int)__popcll(mask);
        }
      }
      int M = cnt < CAPQ ? cnt : CAPQ;

      if (M <= 64) {
        nbl[wv][lane] =
            (lane < M) ? (b * NN + (int)(unsigned)(kc[wv][lane] & 0xffffffffu)) : -1;
      } else {
        ull mk[QRANK];
        int rk[QRANK];
#pragma unroll
        for (int q = 0; q < QRANK; q++) {
          int p = lane + q * 64;
          mk[q] = (p < M) ? kc[wv][p] : ~0ull;
          rk[q] = 0;
        }
        int i = 0;
        for (; i + 2 <= M; i += 2) {
          ull ka = kc[wv][i], kb2 = kc[wv][i + 1];
#pragma unroll
          for (int q = 0; q < QRANK; q++)
            rk[q] += (int)(ka < mk[q]) + (int)(kb2 < mk[q]);
        }
        if (i < M) {
          ull ka = kc[wv][i];
#pragma unroll
          for (int q = 0; q < QRANK; q++) rk[q] += (int)(ka < mk[q]);
        }
#pragma unroll
        for (int q = 0; q < QRANK; q++) {
          int p = lane + q * 64;
          if (p < M && rk[q] < KK)
            nbl[wv][rk[q]] = b * NN + (int)(unsigned)(mk[q] & 0xffffffffu);
        }
      }
    }
    __syncthreads();  // nbl + cc visible

    // phase 2: 4 dual-MLP passes (group 0: waves 0-3, group 1: waves 4-7)
    const int grp = wv >> 2, lw = wv & 3;
    for (int p = 0; p < 4; ++p) {
      const int ci = p * 2 + grp;
      const int* nl = nbl[ci];
      const float cx = cc[ci][0], cy = cc[ci][1], cz = cc[ci][2];
      const int r = lw * 16 + lrow;
      const int j = nl[r];

      bf16x8 a0 = (bf16x8)0, a1 = (bf16x8)0;
      if (j >= 0) {
        const float rx = pos[j * 3 + 0] - cx;
        const float ry = pos[j * 3 + 1] - cy;
        const float rz = pos[j * 3 + 2] - cz;
        const unsigned short* yr = y1b + (size_t)j * H1c;
        uint4 vlo = *(const uint4*)(yr + 8 * g16);
        uint4 vhi = *(const uint4*)(yr + 32 + 8 * g16);
        const unsigned* plo = (const unsigned*)&vlo;
        const unsigned* phi = (const unsigned*)&vhi;
#pragma unroll
        for (int q = 0; q < 4; ++q) {
          unsigned u = plo[q];
          int k0 = 8 * g16 + 2 * q;
          float e0 = __uint_as_float(u << 16) + rx * w1r[0][k0] + ry * w1r[1][k0] +
                     rz * w1r[2][k0];
          float e1 = __uint_as_float(u & 0xffff0000u) + rx * w1r[0][k0 + 1] +
                     ry * w1r[1][k0 + 1] + rz * w1r[2][k0 + 1];
          a0[2 * q] = (short)f2bf(fmaxf(e0, 0.f));
          a0[2 * q + 1] = (short)f2bf(fmaxf(e1, 0.f));
          unsigned u2 = phi[q];
          int k1 = 32 + k0;
          float f0 = __uint_as_float(u2 << 16) + rx * w1r[0][k1] + ry * w1r[1][k1] +
                     rz * w1r[2][k1];
          float f1 = __uint_as_float(u2 & 0xffff0000u) + rx * w1r[0][k1 + 1] +
                     ry * w1r[1][k1 + 1] + rz * w1r[2][k1 + 1];
          a1[2 * q] = (short)f2bf(fmaxf(f0, 0.f));
          a1[2 * q + 1] = (short)f2bf(fmaxf(f1, 0.f));
        }
      }

#pragma unroll
      for (int c = 0; c < 4; ++c) {
        float bb = b2[c * 16 + lrow];
        f32x4 acc = {bb, bb, bb, bb};
        acc = __builtin_amdgcn_mfma_f32_16x16x32_bf16(a0, w2f[(c * 2 + 0) * 64 + lane], acc, 0, 0, 0);
        acc = __builtin_amdgcn_mfma_f32_16x16x32_bf16(a1, w2f[(c * 2 + 1) * 64 + lane], acc, 0, 0, 0);
#pragma unroll
        for (int t = 0; t < 4; ++t)
          h2t[wv][4 * g16 + t][c * 16 + lrow] = f2bf(fmaxf(acc[t], 0.f));
      }

      bf16x8 a20 = *(const bf16x8*)&h2t[wv][lrow][8 * g16];
      bf16x8 a21 = *(const bf16x8*)&h2t[wv][lrow][32 + 8 * g16];

      float vmax[8];
#pragma unroll
      for (int c = 0; c < 8; ++c) {
        float bb = b3[c * 16 + lrow];
        f32x4 acc = {bb, bb, bb, bb};
        acc = __builtin_amdgcn_mfma_f32_16x16x32_bf16(a20, w3f[(c * 2 + 0) * 64 + lane], acc, 0, 0, 0);
        acc = __builtin_amdgcn_mfma_f32_16x16x32_bf16(a21, w3f[(c * 2 + 1) * 64 + lane], acc, 0, 0, 0);
        float m = -INFINITY;
#pragma unroll
        for (int t = 0; t < 4; ++t) {
          int rg = lw * 16 + 4 * g16 + t;
          float val = (nl[rg] >= 0) ? fmaxf(acc[t], 0.f) : -INFINITY;
          m = fmaxf(m, val);
        }
        m = fmaxf(m, __shfl_xor(m, 16));
        m = fmaxf(m, __shfl_xor(m, 32));
        vmax[c] = m;
      }
      if (g16 == 0) {
#pragma unroll
        for (int c = 0; c < 8; ++c) red[wv][c * 16 + lrow] = vmax[c];
      }
      __syncthreads();
      if (tid < 256) {
        const int which = tid >> 7, col = tid & 127;
        const float* rb = red[which * 4];
        float m = fmaxf(fmaxf(rb[col], rb[128 + col]),
                        fmaxf(rb[256 + col], rb[384 + col]));
        x_out[(size_t)(g0 + p * 2 + which) * H3c + col] = m;
      }
      __syncthreads();  // retire red/h2t before next pass
    }
  }
}

extern "C" void kernel_launch(void* const* d_in, const int* in_sizes, int n_in,
                              void* d_out, int out_size, void* d_ws, size_t ws_size,
                              hipStream_t stream) {
  const float* x = (const float*)d_in[0];
  const float* pos = (const float*)d_in[1];
  // d_in[2] = batch (int32) unused: clouds are equal-size by construction
  const float* W1 = (const float*)d_in[3];
  const float* b1 = (const float*)d_in[4];
  const float* W2 = (const float*)d_in[5];
  const float* b2 = (const float*)d_in[6];
  const float* W3 = (const float*)d_in[7];
  const float* b3 = (const float*)d_in[8];

  float* out = (float*)d_out;
  float* x_out = out;                                // [B*S, 128]
  float* pos_out = out + (size_t)BB * SS * H3c;      // [B*S, 3]
  float* batch_out = pos_out + (size_t)BB * SS * 3;  // [B*S]

  const size_t y1_bytes = (size_t)BB * NN * H1c * sizeof(unsigned short);  // 4 MB
  const size_t w2p_bytes = 4096 * sizeof(unsigned short);
  const size_t w3p_bytes = 8192 * sizeof(unsigned short);
  const size_t pln_bytes = (size_t)BB * NN * sizeof(float);   // 128 KB each
  const size_t posw_bytes = (size_t)BB * SS * 3 * sizeof(float);  // 192 KB
  const size_t sync_bytes = 64 * 32 * sizeof(int) + 128;          // flags + ycnt
  const size_t need =
      y1_bytes + w2p_bytes + w3p_bytes + 3 * pln_bytes + posw_bytes + sync_bytes;
  if (ws_size < need) return;
  char* p = (char*)d_ws;
  unsigned short* y1b = (unsigned short*)p;            p += y1_bytes;
  unsigned short* w2p = (unsigned short*)p;            p += w2p_bytes;
  unsigned short* w3p = (unsigned short*)p;            p += w3p_bytes;
  float* xpln = (float*)p;                             p += pln_bytes;
  float* ypln = (float*)p;                             p += pln_bytes;
  float* zpln = (float*)p;                             p += pln_bytes;
  float* posw = (float*)p;                             p += posw_bytes;
  int* flags = (int*)p;            // 64 flags, 128 B apart
  int* ycnt = flags + 64 * 32;     // 1 int

  // zero sync state on EVERY call (graph replay re-runs this node)
  hipMemsetAsync(flags, 0, sync_bytes, stream);
  fused_kernel<<<BB + 1 + NY1, 512, 0, stream>>>(
      pos, x, W1, b1, W2, W3, b2, b3, pos_out, batch_out, y1b, w2p, w3p, xpln,
      ypln, zpln, posw, flags, ycnt, x_out);
}

// Round 16
// 1221.292 us; speedup vs baseline: 1.0618x; 1.0618x over previous
//
#include <hip/hip_runtime.h>
#include <cstdint>
#include <cstddef>

#define BB 8
#define NN 4096
#define FF 64
#define SS 2048
#define KK 64
#define H1c 64
#define H2c 64
#define H3c 128
#define R2 0.04f
#define CAPQ 304   // ball candidate cap (mean 137, +14 sigma safe)
#define QRANK 5    // ceil(CAPQ/64)
#define NY1 240    // consumer blocks; grid = 8+1+240 = 249 <= 256 CUs

typedef unsigned long long ull;
typedef __attribute__((ext_vector_type(4))) float f32x4;
typedef __attribute__((ext_vector_type(8))) short bf16x8;

__device__ __forceinline__ float d2_exact(float ax, float ay, float az,
                                          float bx, float by, float bz) {
  float dx = __fsub_rn(ax, bx);
  float dy = __fsub_rn(ay, by);
  float dz = __fsub_rn(az, bz);
  return __fadd_rn(__fadd_rn(__fmul_rn(dx, dx), __fmul_rn(dy, dy)), __fmul_rn(dz, dz));
}

__device__ __forceinline__ unsigned short f2bf(float f) {
  unsigned u = __float_as_uint(f);
  return (unsigned short)((u + 0x7fffu + ((u >> 16) & 1u)) >> 16);
}

#define WAVE_MAX_DPP(v)                                                        \
  do {                                                                         \
    v = max(v, __builtin_amdgcn_update_dpp(0, v, 0x111, 0xf, 0xf, true));      \
    v = max(v, __builtin_amdgcn_update_dpp(0, v, 0x112, 0xf, 0xf, true));      \
    v = max(v, __builtin_amdgcn_update_dpp(0, v, 0x114, 0xf, 0xf, true));      \
    v = max(v, __builtin_amdgcn_update_dpp(0, v, 0x118, 0xf, 0xf, true));      \
    v = max(v, __builtin_amdgcn_update_dpp(0, v, 0x142, 0xf, 0xf, true));      \
    v = max(v, __builtin_amdgcn_update_dpp(0, v, 0x143, 0xf, 0xf, true));      \
  } while (0)

// One kernel, 249 blocks x 576 threads (all co-resident, 1 block/CU):
//  blocks 0-7   : FPS waves 0-7 (R12 body) + PUBLISHER wave 8 (posw/flags
//                 write-through stores off the compute waves' drain path)
//  block  8     : weight/plane prep
//  blocks 9-248 : y1 GEMM, then gated ball-query + MFMA MLP items (R14 form)
__global__ __launch_bounds__(576) void fused_kernel(
    const float* __restrict__ pos, const float* __restrict__ x,
    const float* __restrict__ W1, const float* __restrict__ b1,
    const float* __restrict__ W2, const float* __restrict__ W3,
    const float* __restrict__ b2, const float* __restrict__ b3,
    float* __restrict__ pos_out, float* __restrict__ batch_out,
    unsigned short* __restrict__ y1b, unsigned short* __restrict__ w2p,
    unsigned short* __restrict__ w3p, float* __restrict__ xpln,
    float* __restrict__ ypln, float* __restrict__ zpln,
    float* __restrict__ posw, int* __restrict__ flags, int* __restrict__ ycnt,
    float* __restrict__ x_out) {
  __shared__ __align__(16) char smem[49408];  // fps plds | consumer kc/h2t/red/nbl/cc
  __shared__ ull skey[2][8];
  __shared__ float xs[64][65];                      // y1 staging
  __shared__ __align__(16) unsigned short lw2[4096];
  __shared__ __align__(16) unsigned short lw3[8192];
  __shared__ float w1r[3][64];
  const int tid = threadIdx.x;
  const int lane = tid & 63, wv = tid >> 6;

  if (blockIdx.x < BB) {
    // ================= FPS role (compute waves 0-7 + publisher wave 8) ====
    float* plds = (float*)smem;
    const int b = blockIdx.x;
    if (tid < 512) {
      const float4* src = (const float4*)(pos + (size_t)b * NN * 3);
      float4* dstl = (float4*)plds;
#pragma unroll
      for (int k = 0; k < 6; ++k) dstl[tid + k * 512] = src[tid + k * 512];
    }
    __syncthreads();

    float px[8], py[8], pz[8], dmin[8];
    if (tid < 512) {
#pragma unroll
      for (int i = 0; i < 8; ++i) {
        int p = tid * 8 + i;
        px[i] = plds[p * 3 + 0];
        py[i] = plds[p * 3 + 1];
        pz[i] = plds[p * 3 + 2];
        dmin[i] = INFINITY;
      }
    }
    float cx = plds[0], cy = plds[1], cz = plds[2];

    for (int s = 0; s < SS; ++s) {
      if (wv < 8) {
        if (tid == 0) {
          int o = b * SS + s;
          pos_out[o * 3 + 0] = cx;
          pos_out[o * 3 + 1] = cy;
          pos_out[o * 3 + 2] = cz;
        }
#pragma unroll
        for (int i = 0; i < 8; ++i) {
          float d = d2_exact(px[i], py[i], pz[i], cx, cy, cz);
          dmin[i] = fminf(dmin[i], d);
        }
        float m0 = fmaxf(fmaxf(dmin[0], dmin[1]), fmaxf(dmin[2], dmin[3]));
        float m1 = fmaxf(fmaxf(dmin[4], dmin[5]), fmaxf(dmin[6], dmin[7]));
        const float lmax = fmaxf(m0, m1);
        int lidx = 0;
#pragma unroll
        for (int i = 7; i >= 0; --i)
          if (__float_as_int(dmin[i]) == __float_as_int(lmax)) lidx = i;

        const int lv = __float_as_int(lmax);
        int v = lv;
        WAVE_MAX_DPP(v);
        const int wmax = __builtin_amdgcn_readlane(v, 63);
        const ull bal = __ballot(lv == wmax);
        const int wl = (int)__builtin_ctzll(bal);
        const int wli = __builtin_amdgcn_readlane(lidx, wl);
        const int widx = ((wv << 6) + wl) * 8 + wli;
        if (lane == 0)
          skey[s & 1][wv] = ((ull)(unsigned)wmax << 32) | (unsigned)(~widx);
      } else if (lane == 0) {
        // publisher wave: write-through publication. Stores issued here
        // drain at THIS wave's barrier arrival (it's ~500cy early, free).
        const int o = b * SS + s;
        __hip_atomic_store(&posw[o * 3 + 0], cx, __ATOMIC_RELAXED,
                           __HIP_MEMORY_SCOPE_AGENT);
        __hip_atomic_store(&posw[o * 3 + 1], cy, __ATOMIC_RELAXED,
                           __HIP_MEMORY_SCOPE_AGENT);
        __hip_atomic_store(&posw[o * 3 + 2], cz, __ATOMIC_RELAXED,
                           __HIP_MEMORY_SCOPE_AGENT);
        if ((s & 255) == 0 && s > 0) {
          // chunk (s>>8)-1 stores all retired at previous barrier arrivals
          __hip_atomic_store(&flags[b * 8 + (s >> 8) - 1], 1, __ATOMIC_RELAXED,
                             __HIP_MEMORY_SCOPE_AGENT);
        }
      }
      __syncthreads();

      const int buf = s & 1;
      ull ka = skey[buf][0];
#pragma unroll
      for (int q = 1; q < 8; ++q) {
        ull kq = skey[buf][q];
        if (kq > ka) ka = kq;
      }
      const int cur = (int)(~(unsigned)(ka & 0xffffffffu));
      cx = plds[cur * 3 + 0];
      cy = plds[cur * 3 + 1];
      cz = plds[cur * 3 + 2];
    }
    if (wv == 8 && lane == 0) {
      asm volatile("s_waitcnt vmcnt(0)" ::: "memory");
      __hip_atomic_store(&flags[b * 8 + 7], 1, __ATOMIC_RELAXED,
                         __HIP_MEMORY_SCOPE_AGENT);
    }
    if (tid < 512)
      for (int i = tid; i < SS; i += 512) batch_out[b * SS + i] = (float)b;
    return;
  }

  if (blockIdx.x == BB) {
    // ================= prep role =================
    for (int e = tid; e < 4096; e += 576) {
      int j = e & 7, l = (e >> 3) & 63, s = (e >> 9) & 1, c = e >> 10;
      w2p[e] = f2bf(W2[(s * 32 + 8 * (l >> 4) + j) * H2c + c * 16 + (l & 15)]);
    }
    for (int e = tid; e < 8192; e += 576) {
      int j = e & 7, l = (e >> 3) & 63, s = (e >> 9) & 1, c = e >> 10;
      w3p[e] = f2bf(W3[(s * 32 + 8 * (l >> 4) + j) * H3c + c * 16 + (l & 15)]);
    }
    for (int i = tid; i < BB * NN; i += 576) {
      xpln[i] = pos[3 * i + 0];
      ypln[i] = pos[3 * i + 1];
      zpln[i] = pos[3 * i + 2];
    }
    __syncthreads();
    if (tid == 0)
      __hip_atomic_fetch_add(ycnt, 1, __ATOMIC_RELEASE, __HIP_MEMORY_SCOPE_AGENT);
    return;
  }

  // ================= consumer role (R14-proven form) =================
  const int cid = blockIdx.x - BB - 1;  // 0..NY1-1

  // ---- phase A: y1 = x @ W1[0:64,:] + b1 -> bf16 ----
  for (int t = cid; t < 512; t += NY1) {
    const int r0 = t * 64;
    if (tid < 512) {
      const float4* src = (const float4*)(x + (size_t)r0 * FF);
#pragma unroll
      for (int q = 0; q < 2; q++) {
        int p = tid + q * 512;
        float4 v = src[p];
        int row = (p * 4) >> 6, col = (p * 4) & 63;
        xs[row][col + 0] = v.x;
        xs[row][col + 1] = v.y;
        xs[row][col + 2] = v.z;
        xs[row][col + 3] = v.w;
      }
    }
    __syncthreads();
    if (tid < 512) {
      const int c4 = (tid & 15) * 4, kb = (tid >> 4) * 2;
      float acc[2][4];
#pragma unroll
      for (int kq = 0; kq < 2; kq++) {
        acc[kq][0] = b1[c4 + 0];
        acc[kq][1] = b1[c4 + 1];
        acc[kq][2] = b1[c4 + 2];
        acc[kq][3] = b1[c4 + 3];
      }
      for (int f = 0; f < FF; ++f) {
        float4 w = *(const float4*)(W1 + f * H1c + c4);
#pragma unroll
        for (int kq = 0; kq < 2; kq++) {
          float a = xs[kb + kq][f];
          acc[kq][0] += a * w.x;
          acc[kq][1] += a * w.y;
          acc[kq][2] += a * w.z;
          acc[kq][3] += a * w.w;
        }
      }
#pragma unroll
      for (int kq = 0; kq < 2; kq++) {
        ushort4 o;
        o.x = f2bf(acc[kq][0]);
        o.y = f2bf(acc[kq][1]);
        o.z = f2bf(acc[kq][2]);
        o.w = f2bf(acc[kq][3]);
        *(ushort4*)(y1b + (size_t)(r0 + kb + kq) * H1c + c4) = o;
      }
    }
    __syncthreads();
  }
  if (tid == 0)
    __hip_atomic_fetch_add(ycnt, 1, __ATOMIC_RELEASE, __HIP_MEMORY_SCOPE_AGENT);

  // ---- gate: all y1 + prep done (then one cache-inv acquire) ----
  while (__hip_atomic_load(ycnt, __ATOMIC_RELAXED, __HIP_MEMORY_SCOPE_AGENT) <
         NY1 + 1)
    __builtin_amdgcn_s_sleep(32);
  if (lane == 0)
    (void)__hip_atomic_load(ycnt, __ATOMIC_ACQUIRE, __HIP_MEMORY_SCOPE_AGENT);
  __syncthreads();

  // ---- stage weights ----
  {
    const uint4* s2 = (const uint4*)w2p;
    uint4* d2v = (uint4*)lw2;
    for (int i = tid; i < 512; i += 576) d2v[i] = s2[i];
    const uint4* s3 = (const uint4*)w3p;
    uint4* d3v = (uint4*)lw3;
    for (int i = tid; i < 1024; i += 576) d3v[i] = s3[i];
    if (tid < 192) w1r[tid / 64][tid % 64] = W1[(64 + tid / 64) * H1c + (tid % 64)];
  }
  __syncthreads();
  const bf16x8* w2f = (const bf16x8*)lw2;
  const bf16x8* w3f = (const bf16x8*)lw3;

  // consumer LDS views inside smem
  ull(*kc)[CAPQ] = (ull(*)[CAPQ])(smem);                        // 19456 B
  unsigned short(*h2t)[16][88] = (unsigned short(*)[16][88])(smem + 19456);
  float(*red)[128] = (float(*)[128])(smem + 41984);             // 4096 B
  int(*nbl)[64] = (int(*)[64])(smem + 46080);                   // 2048 B
  float(*cc)[4] = (float(*)[4])(smem + 48128);                  // 128 B

  const int lrow = lane & 15, g16 = lane >> 4;

  // ---- item loop: 2048 items x 8 centroids, chunk-major order ----
  for (int it = cid; it < 2048; it += NY1) {
    const int k = it >> 8;            // chunk 0..7
    const int rr = it & 255;
    const int b = rr >> 5;            // cloud
    const int j32 = rr & 31;
    const int g0 = b * SS + k * 256 + j32 * 8;

    while (__hip_atomic_load(&flags[b * 8 + k], __ATOMIC_RELAXED,
                             __HIP_MEMORY_SCOPE_AGENT) == 0)
      __builtin_amdgcn_s_sleep(32);
    asm volatile("" ::: "memory");

    // phase 1: wave wv ball-queries centroid g0+wv (waves 0-7)
    if (wv < 8) {
      const int g = g0 + wv;
      const float cx = __hip_atomic_load(&posw[g * 3 + 0], __ATOMIC_RELAXED,
                                         __HIP_MEMORY_SCOPE_AGENT);
      const float cy = __hip_atomic_load(&posw[g * 3 + 1], __ATOMIC_RELAXED,
                                         __HIP_MEMORY_SCOPE_AGENT);
      const float cz = __hip_atomic_load(&posw[g * 3 + 2], __ATOMIC_RELAXED,
                                         __HIP_MEMORY_SCOPE_AGENT);
      if (lane == 0) {
        cc[wv][0] = cx;
        cc[wv][1] = cy;
        cc[wv][2] = cz;
      }
      const float4* xp4 = (const float4*)(xpln + (size_t)b * NN);
      const float4* yp4 = (const float4*)(ypln + (size_t)b * NN);
      const float4* zp4 = (const float4*)(zpln + (size_t)b * NN);
      const ull lt = (1ull << lane) - 1ull;
      int cnt = 0;
      for (int t = 0; t < 16; ++t) {
        const int f4 = t * 64 + lane;
        float4 xv = xp4[f4], yv = yp4[f4], zv = zp4[f4];
        const int j0 = f4 * 4;
        float dd[4];
        dd[0] = d2_exact(xv.x, yv.x, zv.x, cx, cy, cz);
        dd[1] = d2_exact(xv.y, yv.y, zv.y, cx, cy, cz);
        dd[2] = d2_exact(xv.z, yv.z, zv.z, cx, cy, cz);
        dd[3] = d2_exact(xv.w, yv.w, zv.w, cx, cy, cz);
#pragma unroll
        for (int e = 0; e < 4; ++e) {
          bool pred = (dd[e] <= R2);
          ull mask = __ballot(pred);
          if (pred) {
            int p = cnt + (int)__popcll(mask & lt);
            if (p < CAPQ)
              kc[wv][p] = ((ull)__float_as_uint(dd[e]) << 32) | (unsigned)(j0 + e);
          }
          cnt += (int)__popcll(mask);
        }
      }
      int M = cnt < CAPQ ? cnt : CAPQ;

      if (M <= 64) {
        nbl[wv][lane] =
            (lane < M) ? (b * NN + (int)(unsigned)(kc[wv][lane] & 0xffffffffu)) : -1;
      } else {
        ull mk[QRANK];
        int rk[QRANK];
#pragma unroll
        for (int q = 0; q < QRANK; q++) {
          int p = lane + q * 64;
          mk[q] = (p < M) ? kc[wv][p] : ~0ull;
          rk[q] = 0;
        }
        int i = 0;
        for (; i + 2 <= M; i += 2) {
          ull ka = kc[wv][i], kb2 = kc[wv][i + 1];
#pragma unroll
          for (int q = 0; q < QRANK; q++)
            rk[q] += (int)(ka < mk[q]) + (int)(kb2 < mk[q]);
        }
        if (i < M) {
          ull ka = kc[wv][i];
#pragma unroll
          for (int q = 0; q < QRANK; q++) rk[q] += (int)(ka < mk[q]);
        }
#pragma unroll
        for (int q = 0; q < QRANK; q++) {
          int p = lane + q * 64;
          if (p < M && rk[q] < KK)
            nbl[wv][rk[q]] = b * NN + (int)(unsigned)(mk[q] & 0xffffffffu);
        }
      }
    }
    __syncthreads();  // nbl + cc visible

    // phase 2: 4 dual-MLP passes (group 0: waves 0-3, group 1: waves 4-7)
    const int grp = wv >> 2, lw = wv & 3;
    for (int p = 0; p < 4; ++p) {
      if (wv < 8) {
        const int ci = p * 2 + grp;
        const int* nl = nbl[ci];
        const float cx = cc[ci][0], cy = cc[ci][1], cz = cc[ci][2];
        const int r = lw * 16 + lrow;
        const int j = nl[r];

        bf16x8 a0 = (bf16x8)0, a1 = (bf16x8)0;
        if (j >= 0) {
          const float rx = pos[j * 3 + 0] - cx;
          const float ry = pos[j * 3 + 1] - cy;
          const float rz = pos[j * 3 + 2] - cz;
          const unsigned short* yr = y1b + (size_t)j * H1c;
          uint4 vlo = *(const uint4*)(yr + 8 * g16);
          uint4 vhi = *(const uint4*)(yr + 32 + 8 * g16);
          const unsigned* plo = (const unsigned*)&vlo;
          const unsigned* phi = (const unsigned*)&vhi;
#pragma unroll
          for (int q = 0; q < 4; ++q) {
            unsigned u = plo[q];
            int k0 = 8 * g16 + 2 * q;
            float e0 = __uint_as_float(u << 16) + rx * w1r[0][k0] +
                       ry * w1r[1][k0] + rz * w1r[2][k0];
            float e1 = __uint_as_float(u & 0xffff0000u) + rx * w1r[0][k0 + 1] +
                       ry * w1r[1][k0 + 1] + rz * w1r[2][k0 + 1];
            a0[2 * q] = (short)f2bf(fmaxf(e0, 0.f));
            a0[2 * q + 1] = (short)f2bf(fmaxf(e1, 0.f));
            unsigned u2 = phi[q];
            int k1 = 32 + k0;
            float f0 = __uint_as_float(u2 << 16) + rx * w1r[0][k1] +
                       ry * w1r[1][k1] + rz * w1r[2][k1];
            float f1 = __uint_as_float(u2 & 0xffff0000u) + rx * w1r[0][k1 + 1] +
                       ry * w1r[1][k1 + 1] + rz * w1r[2][k1 + 1];
            a1[2 * q] = (short)f2bf(fmaxf(f0, 0.f));
            a1[2 * q + 1] = (short)f2bf(fmaxf(f1, 0.f));
          }
        }

#pragma unroll
        for (int c = 0; c < 4; ++c) {
          float bb = b2[c * 16 + lrow];
          f32x4 acc = {bb, bb, bb, bb};
          acc = __builtin_amdgcn_mfma_f32_16x16x32_bf16(a0, w2f[(c * 2 + 0) * 64 + lane], acc, 0, 0, 0);
          acc = __builtin_amdgcn_mfma_f32_16x16x32_bf16(a1, w2f[(c * 2 + 1) * 64 + lane], acc, 0, 0, 0);
#pragma unroll
          for (int t = 0; t < 4; ++t)
            h2t[wv][4 * g16 + t][c * 16 + lrow] = f2bf(fmaxf(acc[t], 0.f));
        }

        bf16x8 a20 = *(const bf16x8*)&h2t[wv][lrow][8 * g16];
        bf16x8 a21 = *(const bf16x8*)&h2t[wv][lrow][32 + 8 * g16];

        float vmax[8];
#pragma unroll
        for (int c = 0; c < 8; ++c) {
          float bb = b3[c * 16 + lrow];
          f32x4 acc = {bb, bb, bb, bb};
          acc = __builtin_amdgcn_mfma_f32_16x16x32_bf16(a20, w3f[(c * 2 + 0) * 64 + lane], acc, 0, 0, 0);
          acc = __builtin_amdgcn_mfma_f32_16x16x32_bf16(a21, w3f[(c * 2 + 1) * 64 + lane], acc, 0, 0, 0);
          float m = -INFINITY;
#pragma unroll
          for (int t = 0; t < 4; ++t) {
            int rg = lw * 16 + 4 * g16 + t;
            float val = (nl[rg] >= 0) ? fmaxf(acc[t], 0.f) : -INFINITY;
            m = fmaxf(m, val);
          }
          m = fmaxf(m, __shfl_xor(m, 16));
          m = fmaxf(m, __shfl_xor(m, 32));
          vmax[c] = m;
        }
        if (g16 == 0) {
#pragma unroll
          for (int c = 0; c < 8; ++c) red[wv][c * 16 + lrow] = vmax[c];
        }
      }
      __syncthreads();
      if (tid < 256) {
        const int which = tid >> 7, col = tid & 127;
        const float* rb = red[which * 4];
        float m = fmaxf(fmaxf(rb[col], rb[128 + col]),
                        fmaxf(rb[256 + col], rb[384 + col]));
        x_out[(size_t)(g0 + p * 2 + which) * H3c + col] = m;
      }
      __syncthreads();  // retire red/h2t before next pass
    }
  }
}

extern "C" void kernel_launch(void* const* d_in, const int* in_sizes, int n_in,
                              void* d_out, int out_size, void* d_ws, size_t ws_size,
                              hipStream_t stream) {
  const float* x = (const float*)d_in[0];
  const float* pos = (const float*)d_in[1];
  // d_in[2] = batch (int32) unused: clouds are equal-size by construction
  const float* W1 = (const float*)d_in[3];
  const float* b1 = (const float*)d_in[4];
  const float* W2 = (const float*)d_in[5];
  const float* b2 = (const float*)d_in[6];
  const float* W3 = (const float*)d_in[7];
  const float* b3 = (const float*)d_in[8];

  float* out = (float*)d_out;
  float* x_out = out;                                // [B*S, 128]
  float* pos_out = out + (size_t)BB * SS * H3c;      // [B*S, 3]
  float* batch_out = pos_out + (size_t)BB * SS * 3;  // [B*S]

  const size_t y1_bytes = (size_t)BB * NN * H1c * sizeof(unsigned short);  // 4 MB
  const size_t w2p_bytes = 4096 * sizeof(unsigned short);
  const size_t w3p_bytes = 8192 * sizeof(unsigned short);
  const size_t pln_bytes = (size_t)BB * NN * sizeof(float);   // 128 KB each
  const size_t posw_bytes = (size_t)BB * SS * 3 * sizeof(float);  // 192 KB
  const size_t need =
      y1_bytes + w2p_bytes + w3p_bytes + 3 * pln_bytes + posw_bytes + 512;
  if (ws_size < need) return;
  char* p = (char*)d_ws;
  unsigned short* y1b = (unsigned short*)p;            p += y1_bytes;
  unsigned short* w2p = (unsigned short*)p;            p += w2p_bytes;
  unsigned short* w3p = (unsigned short*)p;            p += w3p_bytes;
  float* xpln = (float*)p;                             p += pln_bytes;
  float* ypln = (float*)p;                             p += pln_bytes;
  float* zpln = (float*)p;                             p += pln_bytes;
  float* posw = (float*)p;                             p += posw_bytes;
  int* flags = (int*)p;        // 64 ints
  int* ycnt = flags + 64;      // 1 int

  // zero sync state on EVERY call (graph replay re-runs this node)
  hipMemsetAsync(flags, 0, 512, stream);
  fused_kernel<<<BB + 1 + NY1, 576, 0, stream>>>(
      pos, x, W1, b1, W2, W3, b2, b3, pos_out, batch_out, y1b, w2p, w3p, xpln,
      ypln, zpln, posw, flags, ycnt, x_out);
}